// Round 4
// baseline (224.460 us; speedup 1.0000x reference)
//
#include <hip/hip_runtime.h>

// TrimZeros: reference masks out columns strictly beyond the last nonzero
// column; those columns are already all-zero in the input, so the op is an
// identity copy. 512 MiB read + 512 MiB write = 1.074 GB HBM, memory-bound.
//
// R1: memcpy blit = 5.12 TB/s. R3: float4 copy with NON-TEMPORAL hints =
// 5.08 TB/s — nt store bypasses L2 write-aggregation, capping write BW
// (harness's plain fill kernel hits 6.7 TB/s through L2 on this chip; m13's
// 6.29 TB/s copy ceiling is a PLAIN float4 copy). This round: plain cached
// loads/stores, unroll 4 for MLP. Target ~170-180 us.

typedef float f4 __attribute__((ext_vector_type(4)));

__global__ __launch_bounds__(256) void trimzeros_copy_f4(
    const f4* __restrict__ src, f4* __restrict__ dst, size_t n4) {
    size_t i = (size_t)blockIdx.x * blockDim.x + threadIdx.x;
    const size_t stride = (size_t)gridDim.x * blockDim.x;
#pragma unroll 4
    for (; i < n4; i += stride) {
        dst[i] = src[i];
    }
}

extern "C" void kernel_launch(void* const* d_in, const int* in_sizes, int n_in,
                              void* d_out, int out_size, void* d_ws, size_t ws_size,
                              hipStream_t stream) {
    const f4* x = (const f4*)d_in[0];
    f4* out = (f4*)d_out;
    // out_size = F*L = 1024*131072 = 134,217,728 floats; divisible by 4.
    const size_t n4 = (size_t)out_size / 4;
    const int block = 256;
    const int grid = 2048;  // 32 waves/CU resident; 64 f4 iterations/thread
    trimzeros_copy_f4<<<grid, block, 0, stream>>>(x, out, n4);
}

// Round 5
// 181.736 us; speedup vs baseline: 1.2351x; 1.2351x over previous
//
#include <hip/hip_runtime.h>

// TrimZeros: reference zeroes columns beyond the last nonzero column; those
// columns are all-zero in the input for ANY input, so the op is bitwise an
// identity copy (signed zeros don't affect absmax). 512 MiB read + 512 MiB
// write = 1.074 GB HBM, memory-bound.
//
// Scorecard: SDMA blit 209.9 us (5.12 TB/s), nt grid-stride 211.5, plain
// grid-stride 224.5. R5: eliminate the two kernel-side handicaps --
// no-loop exact grid (32768 blocks x 256 thr, block = contiguous 16 KiB),
// 4 batched nt loads then 4 nt stores per thread (4x MLP, no bounds checks).
// If this doesn't beat ~205 us, ~5.1 TB/s is the mixed-stream HW ceiling.

typedef float f4 __attribute__((ext_vector_type(4)));

__global__ __launch_bounds__(256) void trimzeros_copy_b4(
    const f4* __restrict__ src, f4* __restrict__ dst) {
    // Block covers f4 indices [blockIdx*1024, blockIdx*1024 + 1024).
    const size_t base = (size_t)blockIdx.x * 1024 + threadIdx.x;
    f4 v0 = __builtin_nontemporal_load(&src[base]);
    f4 v1 = __builtin_nontemporal_load(&src[base + 256]);
    f4 v2 = __builtin_nontemporal_load(&src[base + 512]);
    f4 v3 = __builtin_nontemporal_load(&src[base + 768]);
    __builtin_nontemporal_store(v0, &dst[base]);
    __builtin_nontemporal_store(v1, &dst[base + 256]);
    __builtin_nontemporal_store(v2, &dst[base + 512]);
    __builtin_nontemporal_store(v3, &dst[base + 768]);
}

extern "C" void kernel_launch(void* const* d_in, const int* in_sizes, int n_in,
                              void* d_out, int out_size, void* d_ws, size_t ws_size,
                              hipStream_t stream) {
    const f4* x = (const f4*)d_in[0];
    f4* out = (f4*)d_out;
    // out_size = 1024*131072 = 134,217,728 floats = 33,554,432 f4
    //          = 32768 blocks * 1024 f4/block, exact -- no tail.
    const int grid = (int)((size_t)out_size / 4 / 1024);
    trimzeros_copy_b4<<<grid, 256, 0, stream>>>(x, out);
}